// Round 13
// baseline (695.489 us; speedup 1.0000x reference)
//
#include <hip/hip_runtime.h>

#define HID  256
#define DDYN 5
#define NS   27
#define TS   365
#define BS   4            // batch rows per block
#define NW   8            // waves per block (512 threads)
#define UPW  32           // hidden units owned per wave (two 16-col tiles)
#define NTILE 6           // MFMA tiles per wave: {f,g,o} x {lo,hi}
#define AR   5            // Abuf rows: 0..3 = h batch rows, 4 = permanent zeros
#define SA   272          // Abuf row stride in bf16 elems (8-bank shift/row)
#define G3   768          // 3 gates * 256

typedef short short8 __attribute__((ext_vector_type(8)));
typedef float f32x4  __attribute__((ext_vector_type(4)));

__device__ __forceinline__ unsigned short f2bf(float f) {
    union { float f; unsigned u; } v; v.f = f;
    unsigned r = v.u + 0x7FFFu + ((v.u >> 16) & 1u);   // RNE
    return (unsigned short)(r >> 16);
}
__device__ __forceinline__ float bf2f(unsigned short s) {
    union { unsigned u; float f; } v; v.u = ((unsigned)s) << 16;
    return v.f;
}
__device__ __forceinline__ float bf2f_s(short s) {
    union { unsigned u; float f; } v; v.u = ((unsigned)(unsigned short)s) << 16;
    return v.f;
}
__device__ __forceinline__ float fsig(float x) {
    float e = __builtin_amdgcn_exp2f(-1.4426950408889634f * x);
    return __builtin_amdgcn_rcpf(1.0f + e);
}
__device__ __forceinline__ float ftanh(float x) {
    float e = __builtin_amdgcn_exp2f(2.8853900817779268f * x);
    return 1.0f - 2.0f * __builtin_amdgcn_rcpf(1.0f + e);
}

// History: R7 (736us, exec-mask FAIL) -> R8 (615us WIN, zero-row broadcast)
// -> R9 (617us NEUTRAL, 3-reg diet; WRITE_SIZE stuck at 174 MB).
// Model refinements from R9 counters:
//  * MfmaUtil is pipe-RESIDENCY (42% = 96 MFMA x ~17.8cyc), MFMA issue is
//    only ~11% of step time. Step is LDS-pipe + serialization + spill-drain.
//  * 174 MB spill = 2 dw x q==0 lanes x steps x waves x blocks; structural
//    at the 1024-thread 128 (V+A)/wave cliff. Diet can't fix it.
//
// R10 (third submission; two rounds lost to GPU timeout): 512 threads /
// 8 waves, __launch_bounds__(512,2) -> 256 (V+A)/wave. Each wave owns 32
// units (2 tiles x 3 gates, NTILE=6); each thread runs 2 cells. Budget:
// Bf=192 + acc=24 + ~26 working = ~242 < 256 (phase-B lo/hi cells are
// sequential -> wf/wg/wo sets share physical regs; per-chunk clobber
// bounds A-frag prefetch to ~2). Spill structurally gone. Also: phase-A
// LDS reads halved (A-frag feeds 2x units), 6-way acc ILP, ig back in
// registers, cheaper barrier. Arithmetic BIT-IDENTICAL to R8/R9 -> absmax
// must be exactly 2.441e-4. Risk: TLP halved (2 waves/SIMD). If dur >
// 650us, revert structure and attack via i8 weights in the 128-reg budget.
__global__ __launch_bounds__(512, 2)
void ealstm_kernel(const float* __restrict__ x_dyn,  const float* __restrict__ x_stat,
                   const float* __restrict__ W_i,    const float* __restrict__ b_i,
                   const float* __restrict__ W_f,    const float* __restrict__ b_f,
                   const float* __restrict__ W_g,    const float* __restrict__ b_g,
                   const float* __restrict__ W_o,    const float* __restrict__ b_o,
                   const float* __restrict__ W_head, const float* __restrict__ b_head,
                   float* __restrict__ out)
{
    // LDS: 5440 + 12288 + 12288 + 23360 + 432 = 53808 B
    __shared__ __align__(16) unsigned short Abuf[2][AR * SA]; // h rows 0..3 + zero row 4, double-buffered
    __shared__ __align__(16) float          pre[NW * 384];    // wave-private: 6 tiles x 64
    __shared__ __align__(16) unsigned short WxL[G3 * 8];      // per col: Wx[0..4], bias, 0, 0 (bf16)
    __shared__ __align__(16) unsigned short xcA[TS * 4 * 8];  // per (t,row): x[0..4], 1.0, 0, 0 (bf16)
    __shared__ __align__(16) float          xst[BS * NS];

    const int tid  = threadIdx.x;
    const int bid  = blockIdx.x;
    const int b0   = bid * BS;
    const int lane = tid & 63;
    const int wv   = tid >> 6;        // wave 0..7
    const int q    = lane >> 4;       // quad 0..3 (MFMA K-group)
    const int n    = lane & 15;       // MFMA col-in-tile / A row
    const int up   = lane >> 2;       // unit-local 0..15 (phase B)
    const int r    = lane & 3;        // batch row 0..3 (phase B)
    const int u_lo = wv * UPW + up;        // owned unit, lo tile
    const int u_hi = u_lo + 16;            // owned unit, hi tile

    // ---- init LDS (512-thread strides) ----
    for (int i = tid; i < 2 * AR * SA / 2; i += 512)
        ((unsigned int*)Abuf)[i] = 0u;                 // zero both A buffers (h0 = 0; row 4 stays 0 forever)
    for (int i = tid; i < BS * NS; i += 512)
        xst[i] = x_stat[(b0 + i / NS) * NS + (i % NS)];
    for (int i = tid; i < TS * BS; i += 512) {         // x rows, 16B-aligned per (t,row)
        int t = i >> 2, rr = i & 3;
        const float* xp = x_dyn + ((size_t)(b0 + rr) * TS + t) * DDYN;
        unsigned short* dst = &xcA[(unsigned)i * 8];
        #pragma unroll
        for (int d = 0; d < DDYN; d++) dst[d] = f2bf(xp[d]);
        dst[5] = 0x3F80; dst[6] = 0; dst[7] = 0;
    }
    for (int col = tid; col < G3; col += 512) {
        int gate = col >> 8, hc = col & 255;
        const float* Wg = gate == 0 ? W_f : (gate == 1 ? W_g : W_o);
        const float* bg = gate == 0 ? b_f : (gate == 1 ? b_g : b_o);
        #pragma unroll
        for (int d = 0; d < DDYN; d++) WxL[col * 8 + d] = f2bf(Wg[hc * (DDYN + HID) + d]);
        WxL[col * 8 + 5] = f2bf(bg[hc]);
        WxL[col * 8 + 6] = 0; WxL[col * 8 + 7] = 0;
    }

    // ---- persistent B fragments: 6 tiles x 8 K-chunks x 4 VGPR = 192 regs ----
    short8 Bf[NTILE][8];
    #pragma unroll
    for (int j = 0; j < NTILE; j++) {
        int g    = (j >= 3) ? (j - 3) : j;             // gate index
        int urow = wv * UPW + ((j >= 3) ? 16 : 0) + n; // weight row (hidden unit)
        const float* Wg = g == 0 ? W_f : (g == 1 ? W_g : W_o);
        const float* wrow = Wg + urow * (DDYN + HID) + DDYN;   // skip x-part
        #pragma unroll
        for (int c = 0; c < 8; c++) {
            int k0 = c * 32 + q * 8;
            short8 fr;
            #pragma unroll
            for (int e = 0; e < 8; e++) fr[e] = (short)f2bf(wrow[k0 + e]);
            Bf[j][c] = fr;
        }
    }
    __syncthreads();

    // ---- i_gate for this thread's two cells (registers: budget allows) ----
    float ig_lo, ig_hi, cst_lo = 0.f, cst_hi = 0.f;
    {
        float a0 = b_i[u_lo], a1 = b_i[u_hi];
        for (int s = 0; s < NS; s++) {
            float xs = xst[r * NS + s];
            a0 += xs * W_i[u_lo * NS + s];
            a1 += xs * W_i[u_hi * NS + s];
        }
        ig_lo = fsig(a0); ig_hi = fsig(a1);
    }
    __syncthreads();

    const int aoff  = (n < 4 ? n : 4) * SA;   // rows 4..15 -> shared zero row (LDS broadcast)
    const int pbase = wv * 384 + lane;        // phase-B read base (lo tile, gate 0)

    // One LSTM step: PA/PB are compile-time LDS bases after macro expansion.
#define STEP(PA, PB, T)                                                        \
    {                                                                          \
        f32x4 acc[NTILE];                                                      \
        _Pragma("unroll")                                                      \
        for (int j = 0; j < NTILE; j++) acc[j] = (f32x4){0.f, 0.f, 0.f, 0.f}; \
        _Pragma("unroll")                                                      \
        for (int c = 0; c < 8; c++) {                                          \
            short8 a = *(const short8*)&(PA)[aoff + c * 32 + q * 8];           \
            _Pragma("unroll")                                                  \
            for (int j = 0; j < NTILE; j++)                                    \
                acc[j] = __builtin_amdgcn_mfma_f32_16x16x32_bf16(              \
                    a, Bf[j][c], acc[j], 0, 0, 0);                             \
            __asm__ volatile("" ::: "memory");                                 \
        }                                                                      \
        if (q == 0) {                                                          \
            _Pragma("unroll")                                                  \
            for (int j = 0; j < NTILE; j++)                                    \
                *(f32x4*)&pre[wv * 384 + j * 64 + n * 4] = acc[j];             \
        }                                                                      \
        __asm__ volatile("s_waitcnt lgkmcnt(0)" ::: "memory");                 \
        {                                                                      \
            short8 xv = *(const short8*)&xcA[(unsigned)((T) * 4 + r) * 8];     \
            /* lo cell */                                                      \
            {                                                                  \
                short8 wf = *(const short8*)&WxL[(u_lo)        * 8];           \
                short8 wg = *(const short8*)&WxL[(256 + u_lo)  * 8];           \
                short8 wo = *(const short8*)&WxL[(512 + u_lo)  * 8];           \
                float pf = pre[pbase]       + bf2f_s(wf[5]);                   \
                float pg = pre[pbase + 64]  + bf2f_s(wg[5]);                   \
                float po = pre[pbase + 128] + bf2f_s(wo[5]);                   \
                _Pragma("unroll")                                              \
                for (int d = 0; d < DDYN; d++) {                               \
                    float xd = bf2f_s(xv[d]);                                  \
                    pf += xd * bf2f_s(wf[d]);                                  \
                    pg += xd * bf2f_s(wg[d]);                                  \
                    po += xd * bf2f_s(wo[d]);                                  \
                }                                                              \
                float f  = fsig(pf);                                           \
                float g_ = ftanh(pg);                                          \
                float o  = fsig(po);                                           \
                cst_lo = f * cst_lo + ig_lo * g_;                              \
                float h = o * ftanh(cst_lo);                                   \
                (PB)[r * SA + u_lo] = f2bf(h);                                 \
            }                                                                  \
            /* hi cell */                                                      \
            {                                                                  \
                short8 wf = *(const short8*)&WxL[(u_hi)        * 8];           \
                short8 wg = *(const short8*)&WxL[(256 + u_hi)  * 8];           \
                short8 wo = *(const short8*)&WxL[(512 + u_hi)  * 8];           \
                float pf = pre[pbase + 192] + bf2f_s(wf[5]);                   \
                float pg = pre[pbase + 256] + bf2f_s(wg[5]);                   \
                float po = pre[pbase + 320] + bf2f_s(wo[5]);                   \
                _Pragma("unroll")                                              \
                for (int d = 0; d < DDYN; d++) {                               \
                    float xd = bf2f_s(xv[d]);                                  \
                    pf += xd * bf2f_s(wf[d]);                                  \
                    pg += xd * bf2f_s(wg[d]);                                  \
                    po += xd * bf2f_s(wo[d]);                                  \
                }                                                              \
                float f  = fsig(pf);                                           \
                float g_ = ftanh(pg);                                          \
                float o  = fsig(po);                                           \
                cst_hi = f * cst_hi + ig_hi * g_;                              \
                float h = o * ftanh(cst_hi);                                   \
                (PB)[r * SA + u_hi] = f2bf(h);                                 \
            }                                                                  \
        }                                                                      \
        __syncthreads();                                                       \
    }

    // ---- time loop, unrolled x2: t=0..363 as 182 pairs, then tail t=364 ----
    {
        unsigned short* const A0 = &Abuf[0][0];
        unsigned short* const A1 = &Abuf[1][0];
        for (int tp = 0; tp < 182; tp++) {
            const int t0 = tp * 2;
            STEP(A0, A1, t0);        // even step: read buf0, write buf1
            STEP(A1, A0, t0 + 1);    // odd  step: read buf1, write buf0
        }
        STEP(A0, A1, 364);           // tail: final h lands in buffer 1
    }
#undef STEP

    // ---- head: out[b] = h . W_head + b_head (TS odd -> final h in buffer 1) ----
    {
        float h0 = bf2f(Abuf[1][r * SA + u_lo]);
        pre[u_lo * 4 + r] = h0 * W_head[u_lo];
        float h1 = bf2f(Abuf[1][r * SA + u_hi]);
        pre[u_hi * 4 + r] = h1 * W_head[u_hi];
    }
    __syncthreads();
    if (tid < 64) {
        f32x4 s = *(const f32x4*)&pre[tid * 4];
        #pragma unroll
        for (int k = 1; k < 4; k++) {
            f32x4 v = *(const f32x4*)&pre[(tid + k * 64) * 4];
            #pragma unroll
            for (int rr = 0; rr < BS; rr++) s[rr] += v[rr];
        }
        #pragma unroll
        for (int off = 32; off > 0; off >>= 1)
            #pragma unroll
            for (int rr = 0; rr < BS; rr++) s[rr] += __shfl_down(s[rr], off, 64);
        if (tid == 0) {
            float bh = b_head[0];
            #pragma unroll
            for (int rr = 0; rr < BS; rr++) out[b0 + rr] = s[rr] + bh;
        }
    }
}

extern "C" void kernel_launch(void* const* d_in, const int* in_sizes, int n_in,
                              void* d_out, int out_size, void* d_ws, size_t ws_size,
                              hipStream_t stream) {
    ealstm_kernel<<<256, 512, 0, stream>>>(
        (const float*)d_in[0],  (const float*)d_in[1],  (const float*)d_in[2],
        (const float*)d_in[3],  (const float*)d_in[4],  (const float*)d_in[5],
        (const float*)d_in[6],  (const float*)d_in[7],  (const float*)d_in[8],
        (const float*)d_in[9],  (const float*)d_in[10], (const float*)d_in[11],
        (float*)d_out);
}